// Round 5
// baseline (386.276 us; speedup 1.0000x reference)
//
#include <hip/hip_runtime.h>

// CombinedBandPassFilter, single fused kernel (no prep, no d_ws):
//   out[b, band, t] = sum_k H[band,k] * x[b, t+k-384]
// bf16 3-term split MFMA (xh*hh + xl*hh + xh*hl), fp32 acc.
//
// Round-4 structure (resubmitted round-5 after infra timeout):
//   - BN=256 time-tile/block; 4 waves x (q=0..3) x 3 band-tiles of 16x16x32.
//   - x window -> 4 shifted bf16 hi/lo LDS copies once per block (round-3
//     layout, measured conflict-free); aligned ds_read_b64 B-fragments.
//   - A-fragments built INLINE per wave from raw fp32 kern (L1/L2-hot scalar
//     loads + RNE-hi / trunc-lo pack). Rows band>=40 are clamped to row 39:
//     their MFMA outputs are garbage but never stored (D-rows independent).
//   - barrier-free 24-step K-loop + k=768 tail step.

typedef __attribute__((ext_vector_type(8))) short short8;
typedef __attribute__((ext_vector_type(4))) float f32x4;

#define T_LEN   32768
#define BATCH   32
#define NBANDS  40
#define KROW    769
#define PADL    384
#define BN      256
#define NTILES  128            // tiles per batch
#define CP      1104           // copy stride (elems); 1104 % 64 == 16 -> +8 banks/copy
#define NCHUNK  528            // 4 copies * 132 eight-elem chunks (1056 elems/copy)

__device__ __forceinline__ ushort f2bf(float f) {          // RNE float->bf16
    unsigned u = __float_as_uint(f);
    return (ushort)((u + 0x7FFFu + ((u >> 16) & 1u)) >> 16);
}
__device__ __forceinline__ float bf2f(ushort h) {
    return __uint_as_float(((unsigned)h) << 16);
}
// two fp32 -> packed bf16 pair: hi = RNE(a),RNE(b); lo = trunc residuals
__device__ __forceinline__ void cvt_pair(float a, float b,
                                         unsigned& hi, unsigned& lo) {
    const unsigned ua = __float_as_uint(a), ub = __float_as_uint(b);
    const unsigned ra = ua + 0x7FFFu + ((ua >> 16) & 1u);
    const unsigned rb = ub + 0x7FFFu + ((ub >> 16) & 1u);
    hi = (ra >> 16) | (rb & 0xFFFF0000u);
    const float fa = a - __uint_as_float(ra & 0xFFFF0000u);
    const float fb = b - __uint_as_float(rb & 0xFFFF0000u);
    lo = (__float_as_uint(fa) >> 16) | (__float_as_uint(fb) & 0xFFFF0000u);
}

__global__ __launch_bounds__(256, 3)
void conv_fused(const float* __restrict__ x, const float* __restrict__ kern,
                float* __restrict__ out) {
    __shared__ ushort xsh[4 * CP];     // 4 shifted hi copies (8832 B)
    __shared__ ushort xsl[4 * CP];     // 4 shifted lo copies

    const int tid  = threadIdx.x;
    const int bx   = blockIdx.x;
    const int b    = bx >> 7;
    const int tile = bx & (NTILES - 1);
    const int t0   = tile << 8;
    const float* xb = x + (size_t)b * T_LEN;
    const bool interior = (tile >= 2) && (tile <= 125);

    // ---- stage x: 4 shifted bf16 hi/lo copies, converted once ----
    for (int ci = tid; ci < NCHUNK; ci += 256) {
        const int s = ci & 3, m = ci >> 2;
        const int gbase = t0 - PADL + 8 * m + s;   // copy_s[8m..8m+8) = w[8m+s..]
        float v[8];
        if (interior) {
            #pragma unroll
            for (int j = 0; j < 8; ++j) v[j] = xb[gbase + j];
        } else {
            #pragma unroll
            for (int j = 0; j < 8; ++j) {
                const int g = gbase + j;
                v[j] = (g >= 0 && g < T_LEN) ? xb[g] : 0.f;
            }
        }
        union { ushort u[8]; uint4 q; } hi, lo;
        #pragma unroll
        for (int j = 0; j < 8; ++j) {
            const ushort h = f2bf(v[j]);
            hi.u[j] = h;
            lo.u[j] = f2bf(v[j] - bf2f(h));
        }
        *(uint4*)(xsh + s * CP + 8 * m) = hi.q;
        *(uint4*)(xsl + s * CP + 8 * m) = lo.q;
    }
    __syncthreads();

    const int wave = tid >> 6, l = tid & 63;
    const int nl = l & 15, gl = l >> 4;
    const int cs = nl & 3;

    int off[4];                        // aligned LDS elem offsets per q
    #pragma unroll
    for (int q = 0; q < 4; ++q)
        off[q] = cs * CP + ((wave * 4 + q) * 16 + nl - cs) + 8 * gl;

    // clamped per-lane filter rows (band>=40 -> row 39; outputs never stored)
    const float* hb[3];
    #pragma unroll
    for (int mt = 0; mt < 3; ++mt) {
        const int band = mt * 16 + nl;
        hb[mt] = kern + (size_t)(band < NBANDS ? band : NBANDS - 1) * KROW;
    }

    f32x4 acc[4][3];
    #pragma unroll
    for (int q = 0; q < 4; ++q)
        #pragma unroll
        for (int mt = 0; mt < 3; ++mt)
            acc[q][mt] = (f32x4){0.f, 0.f, 0.f, 0.f};

    for (int c = 0; c < 24; ++c) {
        // B fragments from LDS (2x ds_read_b64 each, conflict-free layout)
        union { unsigned u[4]; short8 s8; } bfh[4], bfl[4];
        #pragma unroll
        for (int q = 0; q < 4; ++q) {
            const ushort* ph = xsh + off[q] + 32 * c;
            const ushort* pl = xsl + off[q] + 32 * c;
            const uint2 h0 = *(const uint2*)ph, h1 = *(const uint2*)(ph + 4);
            const uint2 l0 = *(const uint2*)pl, l1 = *(const uint2*)(pl + 4);
            bfh[q].u[0] = h0.x; bfh[q].u[1] = h0.y;
            bfh[q].u[2] = h1.x; bfh[q].u[3] = h1.y;
            bfl[q].u[0] = l0.x; bfl[q].u[1] = l0.y;
            bfl[q].u[2] = l1.x; bfl[q].u[3] = l1.y;
        }
        const int kb = 32 * c + 8 * gl;
        #pragma unroll
        for (int mt = 0; mt < 3; ++mt) {
            // inline A: 8 raw taps -> hi/lo bf16 fragments
            float r[8];
            #pragma unroll
            for (int j = 0; j < 8; ++j) r[j] = hb[mt][kb + j];
            union { unsigned u[4]; short8 s8; } ah, al;
            #pragma unroll
            for (int p = 0; p < 4; ++p)
                cvt_pair(r[2 * p], r[2 * p + 1], ah.u[p], al.u[p]);
            #pragma unroll
            for (int q = 0; q < 4; ++q) {
                acc[q][mt] = __builtin_amdgcn_mfma_f32_16x16x32_bf16(
                    ah.s8, bfh[q].s8, acc[q][mt], 0, 0, 0);
                acc[q][mt] = __builtin_amdgcn_mfma_f32_16x16x32_bf16(
                    ah.s8, bfl[q].s8, acc[q][mt], 0, 0, 0);
                acc[q][mt] = __builtin_amdgcn_mfma_f32_16x16x32_bf16(
                    al.s8, bfh[q].s8, acc[q][mt], 0, 0, 0);
            }
        }
    }

    // ---- tail tap k = 768 (only j=0 of gl=0 group is live) ----
    {
        union { unsigned u[4]; short8 s8; } bfh[4], bfl[4];
        #pragma unroll
        for (int q = 0; q < 4; ++q) {
            const ushort* ph = xsh + off[q] + 768;
            const ushort* pl = xsl + off[q] + 768;
            const uint2 h0 = *(const uint2*)ph, h1 = *(const uint2*)(ph + 4);
            const uint2 l0 = *(const uint2*)pl, l1 = *(const uint2*)(pl + 4);
            bfh[q].u[0] = h0.x; bfh[q].u[1] = h0.y;
            bfh[q].u[2] = h1.x; bfh[q].u[3] = h1.y;
            bfl[q].u[0] = l0.x; bfl[q].u[1] = l0.y;
            bfl[q].u[2] = l1.x; bfl[q].u[3] = l1.y;
        }
        #pragma unroll
        for (int mt = 0; mt < 3; ++mt) {
            const float r0 = hb[mt][768];
            const unsigned u0 = __float_as_uint(r0);
            const unsigned r  = u0 + 0x7FFFu + ((u0 >> 16) & 1u);
            const float res   = r0 - __uint_as_float(r & 0xFFFF0000u);
            union { unsigned u[4]; short8 s8; } ah, al;
            ah.u[0] = (gl == 0) ? (r >> 16) : 0u;
            al.u[0] = (gl == 0) ? (__float_as_uint(res) >> 16) : 0u;
            ah.u[1] = ah.u[2] = ah.u[3] = 0u;
            al.u[1] = al.u[2] = al.u[3] = 0u;
            #pragma unroll
            for (int q = 0; q < 4; ++q) {
                acc[q][mt] = __builtin_amdgcn_mfma_f32_16x16x32_bf16(
                    ah.s8, bfh[q].s8, acc[q][mt], 0, 0, 0);
                acc[q][mt] = __builtin_amdgcn_mfma_f32_16x16x32_bf16(
                    ah.s8, bfl[q].s8, acc[q][mt], 0, 0, 0);
                acc[q][mt] = __builtin_amdgcn_mfma_f32_16x16x32_bf16(
                    al.s8, bfh[q].s8, acc[q][mt], 0, 0, 0);
            }
        }
    }

    // ---- epilogue: C/D col = lane&15 (=t), row = (lane>>4)*4 + rr (=band) ----
    #pragma unroll
    for (int q = 0; q < 4; ++q) {
        const int t = t0 + (wave * 4 + q) * 16 + nl;
        #pragma unroll
        for (int mt = 0; mt < 3; ++mt)
            #pragma unroll
            for (int rr = 0; rr < 4; ++rr) {
                const int band = mt * 16 + gl * 4 + rr;
                if (band < NBANDS)
                    out[((size_t)b * NBANDS + band) * T_LEN + t] = acc[q][mt][rr];
            }
    }
}

extern "C" void kernel_launch(void* const* d_in, const int* in_sizes, int n_in,
                              void* d_out, int out_size, void* d_ws, size_t ws_size,
                              hipStream_t stream) {
    const float* x    = (const float*)d_in[0];
    const float* kern = (const float*)d_in[1];
    float* out        = (float*)d_out;
    conv_fused<<<BATCH * NTILES, 256, 0, stream>>>(x, kern, out);  // 4096 blocks
}

// Round 6
// 266.398 us; speedup vs baseline: 1.4500x; 1.4500x over previous
//
#include <hip/hip_runtime.h>

// CombinedBandPassFilter as MFMA GEMM (bf16 3-term split, fp32 acc):
//   out[b, band, t] = sum_k H[band,k] * x[b, t+k-384]
// Round-6: R3 structure (pre-packed A in d_ws) + BN=256 (q=0..3 per wave,
// halves A L2 traffic per output) + register double-buffered A fragments
// (manual 2-step unroll, all frag indexing compile-time static).
//   - x window -> 4 shifted bf16 hi/lo LDS copies once per block
//     (layout measured conflict-free in R3/R5); aligned ds_read_b64 B-frags.
//   - barrier-free 25-step K-loop (step 24 = taps 768..799, A zero-padded).

typedef __attribute__((ext_vector_type(8))) short short8;
typedef __attribute__((ext_vector_type(4))) float f32x4;

#define T_LEN   32768
#define BATCH   32
#define NBANDS  40
#define KROW    769
#define NSTEP   25             // 25*32 = 800 padded taps
#define PADL    384
#define BN      256
#define NTILES  128            // time-tiles per batch
#define CP      1104           // copy stride (elems): 2208 B -> +8 banks/copy
#define NCHUNK  528            // 4 copies * 132 eight-elem chunks (1056/copy)

__device__ __forceinline__ ushort f2bf(float f) {          // RNE float->bf16
    unsigned u = __float_as_uint(f);
    return (ushort)((u + 0x7FFFu + ((u >> 16) & 1u)) >> 16);
}
__device__ __forceinline__ float bf2f(ushort h) {
    return __uint_as_float(((unsigned)h) << 16);
}

// Pack H into MFMA A-fragment order: Ah/Al[(c*3+mt)*64 + lane] = 8 bf16
// (band = mt*16 + (lane&15), k = c*32 + 8*(lane>>4) + j), zero-padded.
__global__ void prep_filters(const float* __restrict__ kern,
                             ushort* __restrict__ Ah, ushort* __restrict__ Al) {
    const int blk = blockIdx.x;            // 0..74 = c*3 + mt
    const int c = blk / 3, mt = blk - 3 * c;
    const int l = threadIdx.x;
    const int band = mt * 16 + (l & 15);
    const int kb = c * 32 + 8 * (l >> 4);
    union { ushort u[8]; uint4 v; } ah, al;
    #pragma unroll
    for (int j = 0; j < 8; ++j) {
        const int k = kb + j;
        const float h = (band < NBANDS && k < KROW) ? kern[band * KROW + k] : 0.f;
        const ushort hh = f2bf(h);
        ah.u[j] = hh;
        al.u[j] = f2bf(h - bf2f(hh));
    }
    ((uint4*)Ah)[blk * 64 + l] = ah.v;
    ((uint4*)Al)[blk * 64 + l] = al.v;
}

union frag { uint4 v; short8 s8; unsigned u[4]; };

__global__ __launch_bounds__(256, 4)
void conv_mfma(const float* __restrict__ x,
               const ushort* __restrict__ Ah, const ushort* __restrict__ Al,
               float* __restrict__ out) {
    __shared__ ushort xsh[4 * CP];     // 4 shifted hi copies (8832 B)
    __shared__ ushort xsl[4 * CP];     // 4 shifted lo copies

    const int tid  = threadIdx.x;
    const int bx   = blockIdx.x;
    const int b    = bx >> 7;
    const int tile = bx & (NTILES - 1);
    const int t0   = tile << 8;
    const float* xb = x + (size_t)b * T_LEN;
    const bool interior = (tile >= 2) && (tile <= 125);

    // ---- stage x: 4 shifted bf16 hi/lo copies, converted once ----
    for (int ci = tid; ci < NCHUNK; ci += 256) {
        const int s = ci & 3, m = ci >> 2;
        const int gbase = t0 - PADL + 8 * m + s;   // copy_s[8m..8m+8) = w[8m+s..]
        float v[8];
        if (interior) {
            #pragma unroll
            for (int j = 0; j < 8; ++j) v[j] = xb[gbase + j];
        } else {
            #pragma unroll
            for (int j = 0; j < 8; ++j) {
                const int g = gbase + j;
                v[j] = (g >= 0 && g < T_LEN) ? xb[g] : 0.f;
            }
        }
        union { ushort u[8]; uint4 q; } hi, lo;
        #pragma unroll
        for (int j = 0; j < 8; ++j) {
            const ushort h = f2bf(v[j]);
            hi.u[j] = h;
            lo.u[j] = f2bf(v[j] - bf2f(h));
        }
        *(uint4*)(xsh + s * CP + 8 * m) = hi.q;
        *(uint4*)(xsl + s * CP + 8 * m) = lo.q;
    }
    __syncthreads();

    const int wave = tid >> 6, l = tid & 63;
    const int nl = l & 15, gl = l >> 4;
    const int cs = nl & 3;

    int off[4];                        // aligned LDS elem offsets per q
    #pragma unroll
    for (int q = 0; q < 4; ++q)
        off[q] = cs * CP + ((wave * 4 + q) * 16 + nl - cs) + 8 * gl;

    f32x4 acc[4][3];
    #pragma unroll
    for (int q = 0; q < 4; ++q)
        #pragma unroll
        for (int mt = 0; mt < 3; ++mt)
            acc[q][mt] = (f32x4){0.f, 0.f, 0.f, 0.f};

    const uint4* Ah4 = (const uint4*)Ah + l;
    const uint4* Al4 = (const uint4*)Al + l;

    frag ah0[3], al0[3], ah1[3], al1[3];

    // B-load + 36-MFMA step body (all indices compile-time static)
#define LOAD_A(dsth, dstl, step)                                   \
    {   _Pragma("unroll")                                          \
        for (int mt = 0; mt < 3; ++mt) {                           \
            dsth[mt].v = Ah4[((step) * 3 + mt) * 64];              \
            dstl[mt].v = Al4[((step) * 3 + mt) * 64];              \
        }                                                          \
    }
#define DO_STEP(step, fh, fl)                                      \
    {   _Pragma("unroll")                                          \
        for (int q = 0; q < 4; ++q) {                              \
            const ushort* ph = xsh + off[q] + 32 * (step);         \
            const ushort* pl = xsl + off[q] + 32 * (step);         \
            const uint2 h0 = *(const uint2*)ph;                    \
            const uint2 h1 = *(const uint2*)(ph + 4);              \
            const uint2 l0 = *(const uint2*)pl;                    \
            const uint2 l1 = *(const uint2*)(pl + 4);              \
            frag bh, bl;                                           \
            bh.u[0] = h0.x; bh.u[1] = h0.y;                        \
            bh.u[2] = h1.x; bh.u[3] = h1.y;                        \
            bl.u[0] = l0.x; bl.u[1] = l0.y;                        \
            bl.u[2] = l1.x; bl.u[3] = l1.y;                        \
            _Pragma("unroll")                                      \
            for (int mt = 0; mt < 3; ++mt) {                       \
                acc[q][mt] = __builtin_amdgcn_mfma_f32_16x16x32_bf16( \
                    fh[mt].s8, bh.s8, acc[q][mt], 0, 0, 0);        \
                acc[q][mt] = __builtin_amdgcn_mfma_f32_16x16x32_bf16( \
                    fh[mt].s8, bl.s8, acc[q][mt], 0, 0, 0);        \
                acc[q][mt] = __builtin_amdgcn_mfma_f32_16x16x32_bf16( \
                    fl[mt].s8, bh.s8, acc[q][mt], 0, 0, 0);        \
            }                                                      \
        }                                                          \
    }

    LOAD_A(ah0, al0, 0);
    for (int c = 0; c < NSTEP - 1; c += 2) {       // c = 0,2,...,22
        LOAD_A(ah1, al1, c + 1);                   // prefetch next step
        DO_STEP(c, ah0, al0);
        LOAD_A(ah0, al0, c + 2);                   // c+2 <= 24 ✓
        DO_STEP(c + 1, ah1, al1);
    }
    DO_STEP(NSTEP - 1, ah0, al0);                  // step 24 (zero-padded A)
#undef LOAD_A
#undef DO_STEP

    // ---- epilogue: C/D col = lane&15 (=t), row = (lane>>4)*4 + rr (=band) ----
    #pragma unroll
    for (int q = 0; q < 4; ++q) {
        const int t = t0 + (wave * 4 + q) * 16 + nl;
        #pragma unroll
        for (int mt = 0; mt < 3; ++mt)
            #pragma unroll
            for (int rr = 0; rr < 4; ++rr) {
                const int band = mt * 16 + gl * 4 + rr;
                if (band < NBANDS)
                    out[((size_t)b * NBANDS + band) * T_LEN + t] = acc[q][mt][rr];
            }
    }
}

extern "C" void kernel_launch(void* const* d_in, const int* in_sizes, int n_in,
                              void* d_out, int out_size, void* d_ws, size_t ws_size,
                              hipStream_t stream) {
    const float* x    = (const float*)d_in[0];
    const float* kern = (const float*)d_in[1];
    float* out        = (float*)d_out;
    ushort* Ah = (ushort*)d_ws;                 // 75*64*8 bf16 = 76.8 KB
    ushort* Al = Ah + 75 * 64 * 8;              // + 76.8 KB (ws >= 153.6 KB)
    prep_filters<<<75, 64, 0, stream>>>(kern, Ah, Al);
    conv_mfma<<<BATCH * NTILES, 256, 0, stream>>>(x, Ah, Al, out);  // 4096 blocks
}